// Round 6
// baseline (2273.605 us; speedup 1.0000x reference)
//
#include <hip/hip_runtime.h>

// Problem constants: T=2048, B=256, F=64, H=256, O=1
#define T_STEPS 2048
#define BATCH   256
#define FEAT    64
#define HID     256
#define KAUG    320          // FEAT + HID
#define BPB     8            // batches per block (packed into A-rows 0..7)
#define NBLK    (BATCH/BPB)  // 32 blocks
#define NW      8            // 8 waves = 2 waves/SIMD
#define NTHR    512
#define XTILE   16           // timesteps per x tile
#define NTILES  (T_STEPS/XTILE)
#define PX      96           // padded x row (f16): 192B = 12 slots -> conflict-free
#define PH      288          // padded h row (f16): 576B = 36 slots -> conflict-free

typedef _Float16 half8 __attribute__((ext_vector_type(8)));
typedef _Float16 half4 __attribute__((ext_vector_type(4)));
typedef float    f32x4 __attribute__((ext_vector_type(4)));
typedef float    f32x8 __attribute__((ext_vector_type(8)));

// fast tanh: tanh(z) = 1 - 2/(exp(2z)+1). Saturates correctly at +/-inf.
__device__ __forceinline__ float fast_tanh(float z) {
    float e = __expf(2.0f * z);
    return 1.0f - 2.0f * __builtin_amdgcn_rcpf(e + 1.0f);
}

// R6: batch-pack the MFMA A-rows. R2-R5 all burned 160 MFMAs/CU/step (640 cyc
// = the measured-constant ~600us of MFMA busy time) computing 16 output rows
// and keeping ONE (1 batch). Same 160 MFMAs with A-rows 0..7 = 8 batch
// elements serve 8 recurrence chains -> per-batch MFMA floor drops 16x.
// 32 blocks x 8 batches; idle CUs are free (nothing here scales with CUs).
//  - A-frag row r lives on lanes with (lane&15)==r (same mapping as the
//    B-side col=lane&15 proven in R2-R5; masked-row-0 loads proven R3-R5).
//    A-reads masked to l15<8 (32 lanes/wave).
//  - C-rows 0..7 = lanes 0..31, reg j = row (lane>>4)*4+j (m89-verified).
//  - LDS strides padded so the 32 active lanes of every ds_read_b128 hit 32
//    distinct 16B slots: h rows 576B (36 slots), x rows 192B (12 slots).
//  - fc1: wave w owns batch w, reads h(t-1) from LDS (deferred one step,
//    hides the 6-shuffle chain), single writer per out_buf slot -> NO atomics.
//  - x: register-held ring (16 f32/thread), LDS-written 16 steps after load
//    -> zero vmcnt stalls. One barrier per step.
__global__
__attribute__((amdgpu_flat_work_group_size(NTHR, NTHR), amdgpu_waves_per_eu(2, 2)))
void rnn_kernel(const float* __restrict__ x,    // (T, B, F)
                const float* __restrict__ W0,   // (H, F+H) row-major
                const float* __restrict__ b0,   // (H)
                const float* __restrict__ Wfc,  // (1, H)
                const float* __restrict__ bfc,  // (1)
                float* __restrict__ out)        // (B, T)
{
    const int blk  = blockIdx.x;        // 0..31
    const int B0   = blk * BPB;
    const int tid  = threadIdx.x;
    const int w    = tid >> 6;          // wave 0..7 (also: fc1 batch index)
    const int lane = tid & 63;
    const int l15  = lane & 15;
    const int kg   = lane >> 4;         // k-group 0..3
    const bool arow = (l15 < BPB);      // 32 lanes/wave carry A-rows 0..7

    __shared__ __align__(16) _Float16 h_fb[2][BPB][PH];          // 9.2 KB
    __shared__ __align__(16) _Float16 x_stage[2][XTILE][BPB][PX];// 49.2 KB
    __shared__ __align__(16) float    out_buf[BPB][T_STEPS];     // 64 KB

    // ---- B-frags: wave w owns N-tiles {2w, 2w+1} (neurons 32w..32w+31),
    // all 10 K-chunks. Lane: neuron-in-tile = l15, k = kg*8+e. 80 regs.
    half8 bw[2][10];
#pragma unroll
    for (int nt = 0; nt < 2; ++nt) {
        const float* wp = W0 + ((2 * w + nt) * 16 + l15) * KAUG + kg * 8;
#pragma unroll
        for (int c = 0; c < 10; ++c) {
            const f32x8 v = *reinterpret_cast<const f32x8*>(wp + c * 32);
            bw[nt][c] = __builtin_convertvector(v, half8);
        }
    }

    const float b0e0 = b0[(2 * w) * 16 + l15];       // tile 0 bias (col = l15)
    const float b0e1 = b0[(2 * w + 1) * 16 + l15];   // tile 1 bias
    const f32x4 wfc4 = *reinterpret_cast<const f32x4*>(Wfc + 4 * lane);
    const float bfc_r = bfc[0];

    // x thread mapping: thread <-> (batch bt = w, feat ft); 16 steps held in regs
    const int bt = w;
    const int ft = lane;
    const float* xbase = x + (size_t)(B0 + bt) * FEAT + ft;

    // ---- prologue: zero h_fb; stage x tile 0 to LDS; tile 1 to registers
    {
        unsigned* hz = reinterpret_cast<unsigned*>(&h_fb[0][0][0]);
#pragma unroll
        for (int i = 0; i < 5; ++i) {
            const int idx = tid + i * NTHR;
            if (idx < (int)(2 * BPB * PH / 2)) hz[idx] = 0u;
        }
    }
    float xh[XTILE];
#pragma unroll
    for (int s = 0; s < XTILE; ++s)
        x_stage[0][s][bt][ft] = (_Float16)xbase[(size_t)s * (BATCH * FEAT)];
#pragma unroll
    for (int s = 0; s < XTILE; ++s)
        xh[s] = xbase[(size_t)(XTILE + s) * (BATCH * FEAT)];
    __syncthreads();

    // A-frags persist; non-arow lanes keep zeros (feed discarded C rows 8..15)
    half8 af[10];
#pragma unroll
    for (int c = 0; c < 10; ++c) af[c] = half8{};

    const f32x4 zero4 = {0.f, 0.f, 0.f, 0.f};

    for (int t = 0; t < T_STEPS; ++t) {
        const int cur = t & 1;
        const int nxt = cur ^ 1;
        const int ts  = t & 15;
        const int tb  = (t >> 4) & 1;

        // ---- A-frag reads, masked to 32 lanes (batch = l15, k-group = kg)
        if (arow) {
            const _Float16* xr = &x_stage[tb][ts][l15][kg * 8];
            af[0] = *reinterpret_cast<const half8*>(xr);
            af[1] = *reinterpret_cast<const half8*>(xr + 32);
            const _Float16* hr = &h_fb[cur][l15][kg * 8];
#pragma unroll
            for (int c = 2; c < 10; ++c)
                af[c] = *reinterpret_cast<const half8*>(hr + (c - 2) * 32);
        }

        // ---- deferred fc1 for step t-1: wave w = batch w; h(t-1) is in
        // h_fb[cur]. 6-shuffle chain hides under this step's MFMA phase.
        {
            const half4 hv = *reinterpret_cast<const half4*>(&h_fb[cur][w][4 * lane]);
            const f32x4 hf = __builtin_convertvector(hv, f32x4);
            float p = hf.x * wfc4.x + hf.y * wfc4.y + hf.z * wfc4.z + hf.w * wfc4.w;
#pragma unroll
            for (int m = 1; m <= 32; m <<= 1) p += __shfl_xor(p, m, 64);
            if (lane == 0 && t > 0) out_buf[w][t - 1] = p + bfc_r;
        }

        // ---- MFMA: 4 independent chains (2 tiles x even/odd chunks), depth 5
        f32x4 e0 = __builtin_amdgcn_mfma_f32_16x16x32_f16(af[0], bw[0][0], zero4, 0, 0, 0);
        f32x4 o0 = __builtin_amdgcn_mfma_f32_16x16x32_f16(af[1], bw[0][1], zero4, 0, 0, 0);
        f32x4 e1 = __builtin_amdgcn_mfma_f32_16x16x32_f16(af[0], bw[1][0], zero4, 0, 0, 0);
        f32x4 o1 = __builtin_amdgcn_mfma_f32_16x16x32_f16(af[1], bw[1][1], zero4, 0, 0, 0);
#pragma unroll
        for (int c = 2; c < 10; c += 2) {
            e0 = __builtin_amdgcn_mfma_f32_16x16x32_f16(af[c],     bw[0][c],     e0, 0, 0, 0);
            o0 = __builtin_amdgcn_mfma_f32_16x16x32_f16(af[c + 1], bw[0][c + 1], o0, 0, 0, 0);
            e1 = __builtin_amdgcn_mfma_f32_16x16x32_f16(af[c],     bw[1][c],     e1, 0, 0, 0);
            o1 = __builtin_amdgcn_mfma_f32_16x16x32_f16(af[c + 1], bw[1][c + 1], o1, 0, 0, 0);
        }

        // ---- x staging every 16 steps: LDS-write tile ti+1 from regs loaded
        // 16 steps ago (vmcnt long satisfied); then issue loads for tile ti+2.
        if (ts == 0) {
            const int ti = t >> 4;
            if (ti + 1 < NTILES) {
#pragma unroll
                for (int s = 0; s < XTILE; ++s)
                    x_stage[(ti + 1) & 1][s][bt][ft] = (_Float16)xh[s];
            }
            if (ti + 2 < NTILES) {
#pragma unroll
                for (int s = 0; s < XTILE; ++s)
                    xh[s] = xbase[(size_t)(16 * (ti + 2) + s) * (BATCH * FEAT)];
            }
        }

        // ---- epilogue: C rows 0..7 = lanes 0..31, reg j -> batch (lane>>4)*4+j
        if (lane < 32) {
            const int bq = (lane >> 4) * 4;       // batch quad base
#pragma unroll
            for (int j = 0; j < 4; ++j) {
                const float hA = fast_tanh(e0[j] + o0[j] + b0e0);
                const float hB = fast_tanh(e1[j] + o1[j] + b0e1);
                h_fb[nxt][bq + j][(2 * w) * 16 + l15]       = (_Float16)hA;
                h_fb[nxt][bq + j][(2 * w + 1) * 16 + l15]   = (_Float16)hB;
            }
        }

        __syncthreads();   // h(t), x_stage, out_buf[t-1] settled; 1 barrier/step
    }

    // ---- tail: fc1 for t = T-1 (h(2047) is in h_fb[0])
    {
        const half4 hv = *reinterpret_cast<const half4*>(&h_fb[0][w][4 * lane]);
        const f32x4 hf = __builtin_convertvector(hv, f32x4);
        float p = hf.x * wfc4.x + hf.y * wfc4.y + hf.z * wfc4.z + hf.w * wfc4.w;
#pragma unroll
        for (int m = 1; m <= 32; m <<= 1) p += __shfl_xor(p, m, 64);
        if (lane == 0) out_buf[w][T_STEPS - 1] = p + bfc_r;
    }
    __syncthreads();

    // ---- epilogue: coalesced store; out_buf row bt written only by wave bt
    const float* src = &out_buf[bt][0];
    float* dst = out + (size_t)(B0 + bt) * T_STEPS;
#pragma unroll
    for (int i = 0; i < 8; ++i) {
        const int idx = i * 256 + ft * 4;
        *reinterpret_cast<f32x4*>(dst + idx) =
            *reinterpret_cast<const f32x4*>(src + idx);
    }
}

extern "C" void kernel_launch(void* const* d_in, const int* in_sizes, int n_in,
                              void* d_out, int out_size, void* d_ws, size_t ws_size,
                              hipStream_t stream) {
    const float* x   = (const float*)d_in[0];
    const float* W0  = (const float*)d_in[1];
    const float* b0  = (const float*)d_in[2];
    const float* Wfc = (const float*)d_in[3];
    const float* bfc = (const float*)d_in[4];
    // d_in[5] = feature_n == 0 -> no autoregressive tail
    float* out = (float*)d_out;

    rnn_kernel<<<dim3(NBLK), dim3(NTHR), 0, stream>>>(x, W0, b0, Wfc, bfc, out);
}